// Round 5
// baseline (389.102 us; speedup 1.0000x reference)
//
#include <hip/hip_runtime.h>
#include <hip/hip_cooperative_groups.h>
#include <math.h>

namespace cg = cooperative_groups;

#define NB 8            // batch
#define NPIX 262144     // 512*512
#define NBINS 2048
#define TPB 256
#define GRID 512        // coop grid: 2 blocks/CU on 256 CUs (2x co-residency margin)
#define BPS 64          // blocks per sample (coop)
#define PPB 4096        // pixels per block (coop) -> 16 per thread
#define EPS2 1e-12f
#define NOTK 0xFFFFFFFFu

struct SelState { unsigned b1; unsigned rem; unsigned k; unsigned pad; };

#define F4E(v,j) (((const float*)&(v))[j])
#define I4E(v,j) (((const int*)&(v))[j])

__device__ __forceinline__ void pixel_vals(float a, float p,
                                           float i0, float i1, float i2,
                                           float f0, float f1, float f2,
                                           float g0, float g1, float g2,
                                           float& d, float& dc)
{
    float diff = a * (1.0f / 255.0f) - p;
    d = sqrtf(diff * diff + EPS2);
    float om = 1.0f - p;
    float e0 = i0 - (f0 * p + om * g0);
    float e1 = i1 - (f1 * p + om * g1);
    float e2 = i2 - (f2 * p + om * g2);
    dc = sqrtf(e0 * e0 + EPS2) + sqrtf(e1 * e1 + EPS2) + sqrtf(e2 * e2 + EPS2);
}

// ============================ COOPERATIVE FUSED PATH ============================
// ws zero region (contiguous, 98336 words): gcnt[16w] | sumgt[16w] | h1c | h2c | h2s
__global__ __launch_bounds__(TPB, 4) void k_fused(
    const float* __restrict__ image, const float* __restrict__ alpha,
    const float* __restrict__ pred, const int* __restrict__ trimap,
    const float* __restrict__ fg, const float* __restrict__ bg,
    unsigned* __restrict__ gcnt, float* __restrict__ sumgt,
    unsigned* __restrict__ h1c, unsigned* __restrict__ h2c, float* __restrict__ h2s,
    SelState* __restrict__ st, float* __restrict__ out)
{
    cg::grid_group grid = cg::this_grid();
    const int tid = threadIdx.x;
    const int bid = blockIdx.x;

    __shared__ unsigned hc[2 * NBINS];   // 16 KB level-1 count histogram (d | dc)
    __shared__ unsigned ubuf[2 * TPB + 8];
    __shared__ float    fbuf[2 * TPB + 8];

    // ---- phase 0: zero counters + init st + zero out ----
    {
        const unsigned ZWORDS = 32 + 3 * 16 * NBINS;   // 98336
        unsigned gtid = (unsigned)bid * TPB + (unsigned)tid;
        for (unsigned i = gtid; i < ZWORDS; i += (unsigned)GRID * TPB) gcnt[i] = 0u;
        if (gtid < 16) { st[gtid].b1 = NOTK; st[gtid].rem = 0; st[gtid].k = 0; }
        if (gtid == 0) out[0] = 0.f;
    }

    // ---- phase A: compute d/dc into registers, LDS count-hist, count unknown ----
    const int s = bid >> 6;          // BPS == 64
    const int chunk = bid & 63;
    const int pbase = s * NPIX + chunk * PPB;
    const int cbase = s * 3 * NPIX + chunk * PPB;

    for (int i = tid; i < 2 * NBINS; i += TPB) hc[i] = 0u;
    __syncthreads();

    const float md  = sqrtf(EPS2);
    const float mdc = md + md + md;
    const unsigned mdbits  = __float_as_uint(md);
    const unsigned mdcbits = __float_as_uint(mdc);

    float4 dv[4], cv[4];
    unsigned nUnk = 0;

    for (int it = 0; it < 4; ++it) {
        const int off = it * (TPB * 4) + tid * 4;
        int4   tm = *(const int4*)(trimap + pbase + off);
        float4 al = *(const float4*)(alpha + pbase + off);
        float4 pr = *(const float4*)(pred + pbase + off);
        float4 i0 = *(const float4*)(image + cbase + off);
        float4 i1 = *(const float4*)(image + cbase + NPIX + off);
        float4 i2 = *(const float4*)(image + cbase + 2 * NPIX + off);
        float4 f0 = *(const float4*)(fg + cbase + off);
        float4 f1 = *(const float4*)(fg + cbase + NPIX + off);
        float4 f2 = *(const float4*)(fg + cbase + 2 * NPIX + off);
        float4 g0 = *(const float4*)(bg + cbase + off);
        float4 g1 = *(const float4*)(bg + cbase + NPIX + off);
        float4 g2 = *(const float4*)(bg + cbase + 2 * NPIX + off);
#pragma unroll
        for (int j = 0; j < 4; ++j) {
            float d, dcv;
            if (I4E(tm, j) == 128) {
                ++nUnk;
                pixel_vals(F4E(al, j), F4E(pr, j),
                           F4E(i0, j), F4E(i1, j), F4E(i2, j),
                           F4E(f0, j), F4E(f1, j), F4E(f2, j),
                           F4E(g0, j), F4E(g1, j), F4E(g2, j), d, dcv);
                atomicAdd(&hc[__float_as_uint(d) >> 21], 1u);
                atomicAdd(&hc[NBINS + (__float_as_uint(dcv) >> 21)], 1u);
            } else {
                d = md; dcv = mdc;
            }
            ((float*)&dv[it])[j] = d;
            ((float*)&cv[it])[j] = dcv;
        }
    }

    // masked mass aggregated per wave; unknown count per block
    unsigned u = nUnk;
#pragma unroll
    for (int o = 32; o > 0; o >>= 1) u += __shfl_down(u, o);
    if ((tid & 63) == 0) {
        unsigned m = 1024u - u;   // 16 px/thread * 64 lanes
        if (m) {
            atomicAdd(&hc[mdbits >> 21], m);
            atomicAdd(&hc[NBINS + (mdcbits >> 21)], m);
        }
        ubuf[tid >> 6] = u;
    }
    __syncthreads();
    unsigned blockU = (tid == 0) ? (ubuf[0] + ubuf[1] + ubuf[2] + ubuf[3]) : 0u;

    grid.sync();   // #1: zeroing complete; local hists complete

    if (tid == 0) atomicAdd(&gcnt[s], blockU);
    for (int i = tid; i < 2 * NBINS; i += TPB) {
        unsigned c = hc[i];
        if (c) atomicAdd(&h1c[((s << 1) + (i >= NBINS ? 1 : 0)) * NBINS + (i & (NBINS - 1))], c);
    }

    grid.sync();   // #2: h1c, gcnt complete

    // ---- select1: blocks 0..15 ----
    if (bid < 2 * NB) {
        const int unit = bid;
        const unsigned* hg = h1c + unit * NBINS;
        unsigned count = gcnt[unit >> 1];
        int k = (int)floorf((float)count * 0.7f);
        unsigned pc = 0;
#pragma unroll
        for (int j = 0; j < NBINS / TPB; ++j) pc += hg[tid * (NBINS / TPB) + j];
        ubuf[tid] = pc;
        __syncthreads();
        if (tid == 0) {
            unsigned c = 0;
            ubuf[TPB + TPB] = 0u;
            for (int i = TPB - 1; i >= 0; --i) { c += ubuf[i]; ubuf[TPB + i] = c; }
        }
        __syncthreads();
        if (k > 0) {
            unsigned above = ubuf[TPB + tid + 1];
            if (above < (unsigned)k && (unsigned)k <= ubuf[TPB + tid]) {
                unsigned c = above;
                int b1 = tid * (NBINS / TPB);
                for (int j = NBINS / TPB - 1; j >= 0; --j) {
                    unsigned bcn = hg[tid * (NBINS / TPB) + j];
                    if (c + bcn >= (unsigned)k) { b1 = tid * (NBINS / TPB) + j; break; }
                    c += bcn;
                }
                st[unit].b1 = (unsigned)b1;
                st[unit].rem = (unsigned)k - c;   // >= 1
                st[unit].k = (unsigned)k;
            }
        }
        // k<=0: st stays NOTK from phase 0
    }

    grid.sync();   // #3: st complete

    // ---- phase C: register values vs b1 -> sum above + level-2 hist ----
    {
        SelState Sd = st[s * 2 + 0];
        SelState Sc = st[s * 2 + 1];
        float dsum = 0.f, csum = 0.f;
        unsigned* h2cd = h2c + (s * 2 + 0) * NBINS;
        float*    h2sd = h2s + (s * 2 + 0) * NBINS;
        unsigned* h2cc = h2c + (s * 2 + 1) * NBINS;
        float*    h2sc = h2s + (s * 2 + 1) * NBINS;
        for (int it = 0; it < 4; ++it) {
#pragma unroll
            for (int j = 0; j < 4; ++j) {
                if (Sd.b1 != NOTK) {
                    float val = F4E(dv[it], j);
                    unsigned bits = __float_as_uint(val);
                    unsigned b = bits >> 21;
                    if (b > Sd.b1) dsum += val;
                    else if (b == Sd.b1) {
                        unsigned sb = (bits >> 10) & (NBINS - 1);
                        atomicAdd(&h2cd[sb], 1u);
                        atomicAdd(&h2sd[sb], val);
                    }
                }
                if (Sc.b1 != NOTK) {
                    float val = F4E(cv[it], j);
                    unsigned bits = __float_as_uint(val);
                    unsigned b = bits >> 21;
                    if (b > Sc.b1) csum += val;
                    else if (b == Sc.b1) {
                        unsigned sb = (bits >> 10) & (NBINS - 1);
                        atomicAdd(&h2cc[sb], 1u);
                        atomicAdd(&h2sc[sb], val);
                    }
                }
            }
        }
#pragma unroll
        for (int o = 32; o > 0; o >>= 1) { dsum += __shfl_down(dsum, o); csum += __shfl_down(csum, o); }
        if ((tid & 63) == 0) { fbuf[tid >> 6] = dsum; fbuf[4 + (tid >> 6)] = csum; }
        __syncthreads();
        if (tid == 0) {
            float td = fbuf[0] + fbuf[1] + fbuf[2] + fbuf[3];
            float tc = fbuf[4] + fbuf[5] + fbuf[6] + fbuf[7];
            if (Sd.b1 != NOTK) atomicAdd(&sumgt[s * 2 + 0], td);
            if (Sc.b1 != NOTK) atomicAdd(&sumgt[s * 2 + 1], tc);
        }
    }

    grid.sync();   // #4: h2, sumgt complete

    // ---- select2 + final combine ----
    if (bid < 2 * NB) {
        const int unit = bid;
        SelState S = st[unit];
        if (S.b1 != NOTK) {
            const unsigned* hcg = h2c + unit * NBINS;
            const float*    hsg = h2s + unit * NBINS;
            unsigned pc = 0; float ps = 0.f;
#pragma unroll
            for (int j = 0; j < NBINS / TPB; ++j) {
                pc += hcg[tid * (NBINS / TPB) + j];
                ps += hsg[tid * (NBINS / TPB) + j];
            }
            ubuf[tid] = pc; fbuf[tid] = ps;
            __syncthreads();
            if (tid == 0) {
                unsigned c = 0; float sm = 0.f;
                ubuf[2 * TPB] = 0u; fbuf[2 * TPB] = 0.f;
                for (int i = TPB - 1; i >= 0; --i) { c += ubuf[i]; sm += fbuf[i]; ubuf[TPB + i] = c; fbuf[TPB + i] = sm; }
            }
            __syncthreads();
            unsigned k = S.rem;                 // >= 1
            unsigned above = ubuf[TPB + tid + 1];
            if (above < k && k <= ubuf[TPB + tid]) {
                unsigned c = above; float sm = fbuf[TPB + tid + 1];
                unsigned bcn = 0; float bsm = 0.f;
                for (int j = NBINS / TPB - 1; j >= 0; --j) {
                    bcn = hcg[tid * (NBINS / TPB) + j]; bsm = hsg[tid * (NBINS / TPB) + j];
                    if (c + bcn >= k) break;
                    c += bcn; sm += bsm;
                }
                unsigned rem2 = k - c;
                float avg = bsm / (float)bcn;
                float sum_k = sumgt[unit] + sm + (float)rem2 * avg;
                float loss = sum_k / ((float)S.k + 1e-6f);
                atomicAdd(out, 0.0625f * loss);
            }
        }
    }
}

// ============================ FALLBACK PATH (proven R2 pipeline) ============================
#define FB_BPS 256
#define FB_PPB 1024
#define FB_HBPU 32
#define FB_VPB 8192

__global__ __launch_bounds__(TPB) void fb_pass1(
    const float* __restrict__ image, const float* __restrict__ alpha,
    const float* __restrict__ pred, const int* __restrict__ trimap,
    const float* __restrict__ fg, const float* __restrict__ bg,
    unsigned* __restrict__ gcnt, float* __restrict__ vals)
{
    const int tid = threadIdx.x;
    const int s = blockIdx.x >> 8;
    const int chunk = blockIdx.x & 255;
    const int pbase = s * NPIX + chunk * FB_PPB;
    const int cbase = s * 3 * NPIX + chunk * FB_PPB;
    float* vd = vals + (s * 2 + 0) * NPIX + chunk * FB_PPB;
    float* vc = vals + (s * 2 + 1) * NPIX + chunk * FB_PPB;
    const float md  = sqrtf(EPS2);
    const float mdc = md + md + md;
    const int off = tid * 4;
    int4   tm = *(const int4*)(trimap + pbase + off);
    float4 al = *(const float4*)(alpha + pbase + off);
    float4 pr = *(const float4*)(pred + pbase + off);
    float4 i0 = *(const float4*)(image + cbase + off);
    float4 i1 = *(const float4*)(image + cbase + NPIX + off);
    float4 i2 = *(const float4*)(image + cbase + 2 * NPIX + off);
    float4 f0 = *(const float4*)(fg + cbase + off);
    float4 f1 = *(const float4*)(fg + cbase + NPIX + off);
    float4 f2 = *(const float4*)(fg + cbase + 2 * NPIX + off);
    float4 g0 = *(const float4*)(bg + cbase + off);
    float4 g1 = *(const float4*)(bg + cbase + NPIX + off);
    float4 g2 = *(const float4*)(bg + cbase + 2 * NPIX + off);
    unsigned nUnk = 0;
    float4 od, oc;
#pragma unroll
    for (int j = 0; j < 4; ++j) {
        float d, dc;
        if (I4E(tm, j) == 128) {
            ++nUnk;
            pixel_vals(F4E(al, j), F4E(pr, j), F4E(i0, j), F4E(i1, j), F4E(i2, j),
                       F4E(f0, j), F4E(f1, j), F4E(f2, j),
                       F4E(g0, j), F4E(g1, j), F4E(g2, j), d, dc);
        } else { d = md; dc = mdc; }
        ((float*)&od)[j] = d; ((float*)&oc)[j] = dc;
    }
    *(float4*)(vd + off) = od;
    *(float4*)(vc + off) = oc;
    unsigned u = nUnk;
#pragma unroll
    for (int o = 32; o > 0; o >>= 1) u += __shfl_down(u, o);
    __shared__ unsigned wred[4];
    if ((tid & 63) == 0) wred[tid >> 6] = u;
    __syncthreads();
    if (tid == 0) atomicAdd(&gcnt[s], wred[0] + wred[1] + wred[2] + wred[3]);
}

__global__ __launch_bounds__(TPB) void fb_hist1(
    const float* __restrict__ vals, unsigned* __restrict__ h1c)
{
    __shared__ unsigned hc[NBINS];
    const int tid = threadIdx.x;
    for (int i = tid; i < NBINS; i += TPB) hc[i] = 0u;
    __syncthreads();
    const int unit = blockIdx.x >> 5;
    const int chunk = blockIdx.x & 31;
    const float md = sqrtf(EPS2);
    const float mconst = (unit & 1) ? (md + md + md) : md;
    const unsigned mbits = __float_as_uint(mconst);
    const float* v = vals + unit * NPIX + chunk * FB_VPB;
    unsigned mloc = 0;
    for (int it = 0; it < FB_VPB / (TPB * 4); ++it) {
        const int off = (it * TPB + tid) * 4;
        float4 x = *(const float4*)(v + off);
#pragma unroll
        for (int j = 0; j < 4; ++j) {
            unsigned bits = __float_as_uint(F4E(x, j));
            if (bits == mbits) ++mloc;
            else atomicAdd(&hc[bits >> 21], 1u);
        }
    }
#pragma unroll
    for (int o = 32; o > 0; o >>= 1) mloc += __shfl_down(mloc, o);
    if ((tid & 63) == 0 && mloc) atomicAdd(&hc[mbits >> 21], mloc);
    __syncthreads();
    for (int i = tid; i < NBINS; i += TPB) {
        unsigned c = hc[i];
        if (c) atomicAdd(&h1c[unit * NBINS + i], c);
    }
}

__global__ __launch_bounds__(TPB) void fb_select1(
    const unsigned* __restrict__ gcnt, const unsigned* __restrict__ h1c,
    SelState* __restrict__ st)
{
    const int unit = blockIdx.x;
    const int t = threadIdx.x;
    const unsigned* hc = h1c + unit * NBINS;
    unsigned count = gcnt[unit >> 1];
    int k = (int)floorf((float)count * 0.7f);
    __shared__ unsigned spc[TPB];
    unsigned pc = 0;
#pragma unroll
    for (int j = 0; j < NBINS / TPB; ++j) pc += hc[t * (NBINS / TPB) + j];
    spc[t] = pc;
    __syncthreads();
    __shared__ unsigned sufc[TPB + 1];
    if (t == 0) {
        unsigned c = 0; sufc[TPB] = 0;
        for (int i = TPB - 1; i >= 0; --i) { c += spc[i]; sufc[i] = c; }
    }
    __syncthreads();
    if (k <= 0) {
        if (t == 0) { st[unit].b1 = NOTK; st[unit].rem = 0; st[unit].k = 0; }
        return;
    }
    unsigned above = sufc[t + 1];
    if (above < (unsigned)k && (unsigned)k <= sufc[t]) {
        unsigned c = above;
        int b1 = t * (NBINS / TPB);
        for (int j = NBINS / TPB - 1; j >= 0; --j) {
            unsigned bcn = hc[t * (NBINS / TPB) + j];
            if (c + bcn >= (unsigned)k) { b1 = t * (NBINS / TPB) + j; break; }
            c += bcn;
        }
        st[unit].b1 = (unsigned)b1;
        st[unit].rem = (unsigned)k - c;
        st[unit].k = (unsigned)k;
    }
}

__global__ __launch_bounds__(TPB) void fb_pass2(
    const float* __restrict__ vals, const SelState* __restrict__ st,
    unsigned* __restrict__ h2c, float* __restrict__ h2s, float* __restrict__ sumgt)
{
    const int unit = blockIdx.x >> 5;
    const int chunk = blockIdx.x & 31;
    const SelState S = st[unit];
    if (S.b1 == NOTK) return;
    const float* v = vals + unit * NPIX + chunk * FB_VPB;
    unsigned* hcd = h2c + unit * NBINS;
    float*    hsd = h2s + unit * NBINS;
    const int tid = threadIdx.x;
    float lsum = 0.f;
    for (int it = 0; it < FB_VPB / (TPB * 4); ++it) {
        const int off = (it * TPB + tid) * 4;
        float4 x = *(const float4*)(v + off);
#pragma unroll
        for (int j = 0; j < 4; ++j) {
            float val = F4E(x, j);
            unsigned bits = __float_as_uint(val);
            unsigned b = bits >> 21;
            if (b > S.b1) lsum += val;
            else if (b == S.b1) {
                unsigned sb = (bits >> 10) & (NBINS - 1);
                atomicAdd(&hcd[sb], 1u);
                atomicAdd(&hsd[sb], val);
            }
        }
    }
#pragma unroll
    for (int o = 32; o > 0; o >>= 1) lsum += __shfl_down(lsum, o);
    __shared__ float wred[4];
    if ((tid & 63) == 0) wred[tid >> 6] = lsum;
    __syncthreads();
    if (tid == 0) atomicAdd(&sumgt[unit], wred[0] + wred[1] + wred[2] + wred[3]);
}

__global__ __launch_bounds__(TPB) void fb_select2_final(
    const unsigned* __restrict__ h2c, const float* __restrict__ h2s,
    const SelState* __restrict__ st, const float* __restrict__ sumgt,
    float* __restrict__ out)
{
    const int unit = blockIdx.x;
    const int t = threadIdx.x;
    SelState S = st[unit];
    if (S.b1 == NOTK) return;
    const unsigned* hc = h2c + unit * NBINS;
    const float*    hm = h2s + unit * NBINS;
    __shared__ unsigned spc[TPB]; __shared__ float sps[TPB];
    unsigned pc = 0; float ps = 0.f;
#pragma unroll
    for (int j = 0; j < NBINS / TPB; ++j) { pc += hc[t * (NBINS / TPB) + j]; ps += hm[t * (NBINS / TPB) + j]; }
    spc[t] = pc; sps[t] = ps;
    __syncthreads();
    __shared__ unsigned sufc[TPB + 1]; __shared__ float sufs[TPB + 1];
    if (t == 0) {
        unsigned c = 0; float sm = 0.f;
        sufc[TPB] = 0; sufs[TPB] = 0.f;
        for (int i = TPB - 1; i >= 0; --i) { c += spc[i]; sm += sps[i]; sufc[i] = c; sufs[i] = sm; }
    }
    __syncthreads();
    unsigned k = S.rem;
    unsigned above = sufc[t + 1];
    if (above < k && k <= sufc[t]) {
        unsigned c = above; float sm = sufs[t + 1];
        unsigned bcn = 0; float bsm = 0.f;
        for (int j = NBINS / TPB - 1; j >= 0; --j) {
            bcn = hc[t * (NBINS / TPB) + j]; bsm = hm[t * (NBINS / TPB) + j];
            if (c + bcn >= k) break;
            c += bcn; sm += bsm;
        }
        unsigned rem2 = k - c;
        float avg = bsm / (float)bcn;
        float sum_k = sumgt[unit] + sm + (float)rem2 * avg;
        float loss = sum_k / ((float)S.k + 1e-6f);
        atomicAdd(out, 0.0625f * loss);
    }
}

// ============================ HOST ============================
extern "C" void kernel_launch(void* const* d_in, const int* in_sizes, int n_in,
                              void* d_out, int out_size, void* d_ws, size_t ws_size,
                              hipStream_t stream)
{
    const float* image  = (const float*)d_in[0];
    const float* alpha  = (const float*)d_in[1];
    const float* pred   = (const float*)d_in[2];
    const int*   trimap = (const int*)d_in[3];
    const float* fg     = (const float*)d_in[4];
    const float* bg     = (const float*)d_in[5];
    float* out = (float*)d_out;

    char* ws = (char*)d_ws;
    // unified layout: gcnt(64B) | sumgt(64B) | h1c(128K) | h2c(128K) | h2s(128K) | st(256B) | vals(16MB, fallback only)
    unsigned* gcnt  = (unsigned*)(ws);
    float*    sumgt = (float*)(ws + 64);
    unsigned* h1c   = (unsigned*)(ws + 128);
    unsigned* h2c   = (unsigned*)(ws + 128 + 1 * 131072);
    float*    h2s   = (float*)(ws + 128 + 2 * 131072);
    SelState* st    = (SelState*)(ws + 128 + 3 * 131072);
    float*    vals  = (float*)(ws + 524288);

    int maxb = 0;
    hipOccupancyMaxActiveBlocksPerMultiprocessor(&maxb, k_fused, TPB, 0);

    hipError_t err = hipErrorUnknown;
    if (maxb >= 2) {   // GRID=512 needs 2 blocks/CU co-resident
        void* args[] = { (void*)&image, (void*)&alpha, (void*)&pred, (void*)&trimap,
                         (void*)&fg, (void*)&bg,
                         (void*)&gcnt, (void*)&sumgt, (void*)&h1c, (void*)&h2c,
                         (void*)&h2s, (void*)&st, (void*)&out };
        err = hipLaunchCooperativeKernel((void*)k_fused, dim3(GRID), dim3(TPB), args, 0, stream);
    }
    if (err != hipSuccess) {
        // proven multi-kernel fallback
        hipMemsetAsync(d_ws, 0, 128 + 3 * 131072, stream);
        hipMemsetAsync(d_out, 0, sizeof(float), stream);
        fb_pass1<<<NB * FB_BPS, TPB, 0, stream>>>(image, alpha, pred, trimap, fg, bg, gcnt, vals);
        fb_hist1<<<16 * FB_HBPU, TPB, 0, stream>>>(vals, h1c);
        fb_select1<<<16, TPB, 0, stream>>>(gcnt, h1c, st);
        fb_pass2<<<16 * FB_HBPU, TPB, 0, stream>>>(vals, st, h2c, h2s, sumgt);
        fb_select2_final<<<16, TPB, 0, stream>>>(h2c, h2s, st, sumgt, out);
    }
}

// Round 6
// 195.943 us; speedup vs baseline: 1.9858x; 1.9858x over previous
//
#include <hip/hip_runtime.h>
#include <math.h>

#define NB 8             // batch
#define NPIX 262144      // 512*512
#define NBINS1 1024      // level-1: top 10 float bits
#define NBINS2 2048      // level-2: bits 21..11
#define TPB 256
#define BPS 256          // pass1 blocks per sample -> 2048 blocks, 8/CU
#define PPB 1024         // pixels per block (4 per thread)
#define HBPU 32          // pass2 blocks per unit -> 512 blocks
#define VPB 8192         // values per pass2 block
#define EPS2 1e-12f
#define NOTK 0xFFFFFFFFu

struct SelState { unsigned b1; unsigned rem; unsigned k; unsigned pad; };

#define F4E(v,j) (((const float*)&(v))[j])
#define I4E(v,j) (((const int*)&(v))[j])

__device__ __forceinline__ void pixel_vals(float a, float p,
                                           float i0, float i1, float i2,
                                           float f0, float f1, float f2,
                                           float g0, float g1, float g2,
                                           float& d, float& dc)
{
    float diff = a * (1.0f / 255.0f) - p;
    d = sqrtf(diff * diff + EPS2);
    float om = 1.0f - p;
    float e0 = i0 - (f0 * p + om * g0);
    float e1 = i1 - (f1 * p + om * g1);
    float e2 = i2 - (f2 * p + om * g2);
    dc = sqrtf(e0 * e0 + EPS2) + sqrtf(e1 * e1 + EPS2) + sqrtf(e2 * e2 + EPS2);
}

// ---------------- Pass 1: stream inputs -> vals + fused level-1 count hist (1024 bins) ----------------
__global__ __launch_bounds__(TPB) void k_pass1(
    const float* __restrict__ image, const float* __restrict__ alpha,
    const float* __restrict__ pred, const int* __restrict__ trimap,
    const float* __restrict__ fg, const float* __restrict__ bg,
    unsigned* __restrict__ gcnt, unsigned* __restrict__ h1c, float* __restrict__ vals)
{
    __shared__ unsigned hc[2 * NBINS1];   // 8 KB: [0..1024) d, [1024..2048) dc
    const int tid = threadIdx.x;
    for (int i = tid; i < 2 * NBINS1; i += TPB) hc[i] = 0u;
    __syncthreads();

    const int s = blockIdx.x >> 8;        // BPS == 256
    const int chunk = blockIdx.x & 255;
    const int pbase = s * NPIX + chunk * PPB;
    const int cbase = s * 3 * NPIX + chunk * PPB;
    float* vd = vals + (s * 2 + 0) * NPIX + chunk * PPB;
    float* vc = vals + (s * 2 + 1) * NPIX + chunk * PPB;

    const float md  = sqrtf(EPS2);        // masked d value (also min possible d)
    const float mdc = md + md + md;
    const unsigned mdbits  = __float_as_uint(md);
    const unsigned mdcbits = __float_as_uint(mdc);

    const int off = tid * 4;
    int4   tm = *(const int4*)(trimap + pbase + off);
    float4 al = *(const float4*)(alpha + pbase + off);
    float4 pr = *(const float4*)(pred + pbase + off);
    float4 i0 = *(const float4*)(image + cbase + off);
    float4 i1 = *(const float4*)(image + cbase + NPIX + off);
    float4 i2 = *(const float4*)(image + cbase + 2 * NPIX + off);
    float4 f0 = *(const float4*)(fg + cbase + off);
    float4 f1 = *(const float4*)(fg + cbase + NPIX + off);
    float4 f2 = *(const float4*)(fg + cbase + 2 * NPIX + off);
    float4 g0 = *(const float4*)(bg + cbase + off);
    float4 g1 = *(const float4*)(bg + cbase + NPIX + off);
    float4 g2 = *(const float4*)(bg + cbase + 2 * NPIX + off);

    unsigned nUnk = 0, mD = 0, mC = 0;    // masked/min-constant aggregates
    float4 od, oc;
#pragma unroll
    for (int j = 0; j < 4; ++j) {
        float d, dc;
        if (I4E(tm, j) == 128) {
            ++nUnk;
            pixel_vals(F4E(al, j), F4E(pr, j),
                       F4E(i0, j), F4E(i1, j), F4E(i2, j),
                       F4E(f0, j), F4E(f1, j), F4E(f2, j),
                       F4E(g0, j), F4E(g1, j), F4E(g2, j), d, dc);
        } else {
            d = md; dc = mdc;
        }
        unsigned db = __float_as_uint(d), cb = __float_as_uint(dc);
        if (db == mdbits) ++mD; else atomicAdd(&hc[db >> 22], 1u);
        if (cb == mdcbits) ++mC; else atomicAdd(&hc[NBINS1 + (cb >> 22)], 1u);
        ((float*)&od)[j] = d;
        ((float*)&oc)[j] = dc;
    }
    *(float4*)(vd + off) = od;
    *(float4*)(vc + off) = oc;

    unsigned u = nUnk, a = mD, b = mC;
#pragma unroll
    for (int o = 32; o > 0; o >>= 1) {
        u += __shfl_down(u, o); a += __shfl_down(a, o); b += __shfl_down(b, o);
    }
    __shared__ unsigned wred[4];
    if ((tid & 63) == 0) {
        if (a) atomicAdd(&hc[mdbits >> 22], a);
        if (b) atomicAdd(&hc[NBINS1 + (mdcbits >> 22)], b);
        wred[tid >> 6] = u;
    }
    __syncthreads();
    if (tid == 0) atomicAdd(&gcnt[s], wred[0] + wred[1] + wred[2] + wred[3]);

    for (int i = tid; i < 2 * NBINS1; i += TPB) {
        unsigned c = hc[i];
        if (c) atomicAdd(&h1c[((s << 1) + (i >= NBINS1 ? 1 : 0)) * NBINS1 + (i & (NBINS1 - 1))], c);
    }
}

// ---------------- select1 (16 blocks): find b1; also zero h2/sumgt/out ----------------
__global__ __launch_bounds__(TPB) void k_select1(
    const unsigned* __restrict__ gcnt, const unsigned* __restrict__ h1c,
    SelState* __restrict__ st, unsigned* __restrict__ h2c, float* __restrict__ h2s,
    float* __restrict__ sumgt, float* __restrict__ out)
{
    const int unit = blockIdx.x;
    const int t = threadIdx.x;

    // zero this unit's level-2 rows + (block 0) sumgt/out — consumed only after this kernel
    for (int i = t; i < NBINS2; i += TPB) { h2c[unit * NBINS2 + i] = 0u; h2s[unit * NBINS2 + i] = 0.f; }
    if (unit == 0) {
        if (t < 16) sumgt[t] = 0.f;
        if (t == 0) out[0] = 0.f;
    }

    const unsigned* hc = h1c + unit * NBINS1;
    unsigned count = gcnt[unit >> 1];
    int k = (int)floorf((float)count * 0.7f);

    __shared__ unsigned spc[TPB];
    unsigned pc = 0;
#pragma unroll
    for (int j = 0; j < NBINS1 / TPB; ++j) pc += hc[t * (NBINS1 / TPB) + j];
    spc[t] = pc;
    __syncthreads();
    __shared__ unsigned sufc[TPB + 1];
    if (t == 0) {
        unsigned c = 0; sufc[TPB] = 0;
        for (int i = TPB - 1; i >= 0; --i) { c += spc[i]; sufc[i] = c; }
    }
    __syncthreads();
    if (k <= 0) {
        if (t == 0) { st[unit].b1 = NOTK; st[unit].rem = 0; st[unit].k = 0; }
        return;
    }
    unsigned above = sufc[t + 1];
    if (above < (unsigned)k && (unsigned)k <= sufc[t]) {
        unsigned c = above;
        int b1 = t * (NBINS1 / TPB);
        for (int j = NBINS1 / TPB - 1; j >= 0; --j) {
            unsigned bcn = hc[t * (NBINS1 / TPB) + j];
            if (c + bcn >= (unsigned)k) { b1 = t * (NBINS1 / TPB) + j; break; }
            c += bcn;
        }
        st[unit].b1 = (unsigned)b1;
        st[unit].rem = (unsigned)k - c;   // >= 1
        st[unit].k = (unsigned)k;
    }
}

// ---------------- Pass 2: sum above b1; level-2 hist (bits 21..11) for bin == b1 ----------------
__global__ __launch_bounds__(TPB) void k_pass2(
    const float* __restrict__ vals, const SelState* __restrict__ st,
    unsigned* __restrict__ h2c, float* __restrict__ h2s, float* __restrict__ sumgt)
{
    const int unit = blockIdx.x >> 5;     // HBPU == 32
    const int chunk = blockIdx.x & 31;
    const SelState S = st[unit];
    if (S.b1 == NOTK) return;
    const float* v = vals + unit * NPIX + chunk * VPB;
    unsigned* hcd = h2c + unit * NBINS2;
    float*    hsd = h2s + unit * NBINS2;
    const int tid = threadIdx.x;

    const float md = sqrtf(EPS2);
    const float mconst = (unit & 1) ? (md + md + md) : md;
    const unsigned mbits = __float_as_uint(mconst);
    const bool magg = (mbits >> 22) == S.b1;   // masked constant lands in boundary bin?

    float lsum = 0.f;
    unsigned mloc = 0;
    for (int it = 0; it < VPB / (TPB * 4); ++it) {
        const int off = (it * TPB + tid) * 4;
        float4 x = *(const float4*)(v + off);
#pragma unroll
        for (int j = 0; j < 4; ++j) {
            float val = F4E(x, j);
            unsigned bits = __float_as_uint(val);
            unsigned b = bits >> 22;
            if (b > S.b1) {
                lsum += val;
            } else if (b == S.b1) {
                if (bits == mbits) { ++mloc; }   // identical values -> aggregate
                else {
                    unsigned sb = (bits >> 11) & (NBINS2 - 1);
                    atomicAdd(&hcd[sb], 1u);
                    atomicAdd(&hsd[sb], val);
                }
            }
        }
    }
#pragma unroll
    for (int o = 32; o > 0; o >>= 1) { lsum += __shfl_down(lsum, o); mloc += __shfl_down(mloc, o); }
    __shared__ float wred[4];
    if ((tid & 63) == 0) {
        wred[tid >> 6] = lsum;
        if (magg && mloc) {
            unsigned sb = (mbits >> 11) & (NBINS2 - 1);
            atomicAdd(&hcd[sb], mloc);
            atomicAdd(&hsd[sb], (float)mloc * mconst);
        }
    }
    __syncthreads();
    if (tid == 0) atomicAdd(&sumgt[unit], wred[0] + wred[1] + wred[2] + wred[3]);
}

// ---------------- select2 + final combine ----------------
__global__ __launch_bounds__(TPB) void k_select2_final(
    const unsigned* __restrict__ h2c, const float* __restrict__ h2s,
    const SelState* __restrict__ st, const float* __restrict__ sumgt,
    float* __restrict__ out)
{
    const int unit = blockIdx.x;
    const int t = threadIdx.x;
    SelState S = st[unit];
    if (S.b1 == NOTK) return;   // k==0 contributes 0
    const unsigned* hc = h2c + unit * NBINS2;
    const float*    hm = h2s + unit * NBINS2;

    __shared__ unsigned spc[TPB]; __shared__ float sps[TPB];
    unsigned pc = 0; float ps = 0.f;
#pragma unroll
    for (int j = 0; j < NBINS2 / TPB; ++j) { pc += hc[t * (NBINS2 / TPB) + j]; ps += hm[t * (NBINS2 / TPB) + j]; }
    spc[t] = pc; sps[t] = ps;
    __syncthreads();
    __shared__ unsigned sufc[TPB + 1]; __shared__ float sufs[TPB + 1];
    if (t == 0) {
        unsigned c = 0; float sm = 0.f;
        sufc[TPB] = 0; sufs[TPB] = 0.f;
        for (int i = TPB - 1; i >= 0; --i) { c += spc[i]; sm += sps[i]; sufc[i] = c; sufs[i] = sm; }
    }
    __syncthreads();
    unsigned k = S.rem;                 // >= 1, crossing guaranteed
    unsigned above = sufc[t + 1];
    if (above < k && k <= sufc[t]) {
        unsigned c = above; float sm = sufs[t + 1];
        unsigned bcn = 0; float bsm = 0.f;
        for (int j = NBINS2 / TPB - 1; j >= 0; --j) {
            bcn = hc[t * (NBINS2 / TPB) + j]; bsm = hm[t * (NBINS2 / TPB) + j];
            if (c + bcn >= k) break;
            c += bcn; sm += bsm;
        }
        unsigned rem2 = k - c;
        float avg = bsm / (float)bcn;   // 21 known bits -> ~2^-13 relative bin width
        float sum_k = sumgt[unit] + sm + (float)rem2 * avg;
        float loss = sum_k / ((float)S.k + 1e-6f);
        atomicAdd(out, 0.0625f * loss); // 0.5 stage weight / 8 samples, both arrays
    }
}

extern "C" void kernel_launch(void* const* d_in, const int* in_sizes, int n_in,
                              void* d_out, int out_size, void* d_ws, size_t ws_size,
                              hipStream_t stream)
{
    const float* image  = (const float*)d_in[0];
    const float* alpha  = (const float*)d_in[1];
    const float* pred   = (const float*)d_in[2];
    const int*   trimap = (const int*)d_in[3];
    const float* fg     = (const float*)d_in[4];
    const float* bg     = (const float*)d_in[5];
    float* out = (float*)d_out;

    char* ws = (char*)d_ws;
    // layout: gcnt(64B) | sumgt(64B) | h1c(64KB) | h2c(128KB) | h2s(128KB) | st(256B) | vals(16MB)
    unsigned* gcnt  = (unsigned*)(ws);
    float*    sumgt = (float*)(ws + 64);
    unsigned* h1c   = (unsigned*)(ws + 128);
    unsigned* h2c   = (unsigned*)(ws + 128 + 65536);
    float*    h2s   = (float*)(ws + 128 + 65536 + 131072);
    SelState* st    = (SelState*)(ws + 128 + 65536 + 2 * 131072);
    float*    vals  = (float*)(ws + 524288);

    // zero only what pass1 accumulates into (gcnt + h1c); rest zeroed inside select1
    hipMemsetAsync(d_ws, 0, 128 + 65536, stream);
    k_pass1<<<NB * BPS, TPB, 0, stream>>>(image, alpha, pred, trimap, fg, bg, gcnt, h1c, vals);
    k_select1<<<16, TPB, 0, stream>>>(gcnt, h1c, st, h2c, h2s, sumgt, out);
    k_pass2<<<16 * HBPU, TPB, 0, stream>>>(vals, st, h2c, h2s, sumgt);
    k_select2_final<<<16, TPB, 0, stream>>>(h2c, h2s, st, sumgt, out);
}